// Round 3
// baseline (18.417 us; speedup 1.0000x reference)
//
#include <hip/hip_runtime.h>

// x: (B, 65, 12) f32, only [:,0,:12] used. Row stride = 780 floats = 3120 B (16B-aligned).
// MLP: h=relu(q@W1+b1) [12->16]; blk=relu(h@W2+b2) [16->8];
// out = blk@(Ws@Wo) + (bs@Wo+bo) [8->3]  (Ws/Wo fold: no nonlinearity between them)
// d_out layout: out[B*3] then force_prev[B*3] = x[:,0,6:9]
//
// v2b: row loads issued BEFORE weight staging + barrier (overlap HBM latency
// with LDS setup); nontemporal loads/stores via native clang vector type
// (HIP_vector_type<float,4> is rejected by __builtin_nontemporal_load).

typedef float f32x4 __attribute__((ext_vector_type(4)));

__global__ __launch_bounds__(256) void mlp_fused(
    const float* __restrict__ x,
    const float* __restrict__ W1, const float* __restrict__ b1,
    const float* __restrict__ W2, const float* __restrict__ b2,
    const float* __restrict__ Ws, const float* __restrict__ bs,
    const float* __restrict__ Wo, const float* __restrict__ bo,
    float* __restrict__ out, int B)
{
    __shared__ float s[372];
    float* sW1 = s;          // 192 = 12*16
    float* sb1 = s + 192;    // 16
    float* sW2 = s + 208;    // 128 = 16*8
    float* sb2 = s + 336;    // 8
    float* sWc = s + 344;    // 24 = 8*3 folded Ws@Wo
    float* sbc = s + 368;    // 3  folded bs@Wo + bo

    const int t = threadIdx.x;
    const int idx = blockIdx.x * blockDim.x + t;

    // ---- issue the scattered row loads FIRST (latency overlaps staging) ----
    const f32x4* row = reinterpret_cast<const f32x4*>(x + (size_t)idx * 780);
    f32x4 v0 = {0,0,0,0}, v1 = {0,0,0,0}, v2 = {0,0,0,0};
    if (idx < B) {
        v0 = __builtin_nontemporal_load(row);
        v1 = __builtin_nontemporal_load(row + 1);
        v2 = __builtin_nontemporal_load(row + 2);
    }

    // ---- stage weights (uniform, tiny) ----
    if (t < 192) sW1[t] = W1[t];
    if (t < 16)  sb1[t] = b1[t];
    if (t < 128) sW2[t] = W2[t];
    if (t < 8)   sb2[t] = b2[t];
    if (t < 24) {                      // Wc[k][j] = sum_m Ws[k,m]*Wo[m,j]
        int k = t / 3, j = t % 3;
        float acc = 0.f;
        #pragma unroll
        for (int m = 0; m < 16; ++m) acc = fmaf(Ws[k*16 + m], Wo[m*3 + j], acc);
        sWc[t] = acc;
    }
    if (t >= 24 && t < 27) {           // bc[j] = sum_m bs[m]*Wo[m,j] + bo[j]
        int j = t - 24;
        float acc = bo[j];
        #pragma unroll
        for (int m = 0; m < 16; ++m) acc = fmaf(bs[m], Wo[m*3 + j], acc);
        sbc[j] = acc;
    }
    __syncthreads();

    if (idx >= B) return;

    const float q[12] = {v0.x, v0.y, v0.z, v0.w,
                         v1.x, v1.y, v1.z, v1.w,
                         v2.x, v2.y, v2.z, v2.w};

    float h[16];
    #pragma unroll
    for (int j = 0; j < 16; ++j) {
        float acc = sb1[j];
        #pragma unroll
        for (int k = 0; k < 12; ++k) acc = fmaf(q[k], sW1[k*16 + j], acc);
        h[j] = fmaxf(acc, 0.f);
    }

    float blk[8];
    #pragma unroll
    for (int j = 0; j < 8; ++j) {
        float acc = sb2[j];
        #pragma unroll
        for (int k = 0; k < 16; ++k) acc = fmaf(h[k], sW2[k*8 + j], acc);
        blk[j] = fmaxf(acc, 0.f);
    }

    float o[3];
    #pragma unroll
    for (int j = 0; j < 3; ++j) {
        float acc = sbc[j];
        #pragma unroll
        for (int k = 0; k < 8; ++k) acc = fmaf(blk[k], sWc[k*3 + j], acc);
        o[j] = acc;
    }

    float* po = out + (size_t)idx * 3;
    __builtin_nontemporal_store(o[0], po);
    __builtin_nontemporal_store(o[1], po + 1);
    __builtin_nontemporal_store(o[2], po + 2);

    float* pf = out + (size_t)B * 3 + (size_t)idx * 3;
    __builtin_nontemporal_store(q[6], pf);
    __builtin_nontemporal_store(q[7], pf + 1);
    __builtin_nontemporal_store(q[8], pf + 2);
}

extern "C" void kernel_launch(void* const* d_in, const int* in_sizes, int n_in,
                              void* d_out, int out_size, void* d_ws, size_t ws_size,
                              hipStream_t stream) {
    const float* x  = (const float*)d_in[0];
    const float* W1 = (const float*)d_in[1];
    const float* b1 = (const float*)d_in[2];
    const float* W2 = (const float*)d_in[3];
    const float* b2 = (const float*)d_in[4];
    const float* Ws = (const float*)d_in[5];
    const float* bs = (const float*)d_in[6];
    const float* Wo = (const float*)d_in[7];
    const float* bo = (const float*)d_in[8];
    float* out = (float*)d_out;

    const int B = in_sizes[0] / (65 * 12);   // 262144
    const int blocks = (B + 255) / 256;      // 1024

    mlp_fused<<<blocks, 256, 0, stream>>>(x, W1, b1, W2, b2, Ws, bs, Wo, bo, out, B);
}

// Round 4
// 15.410 us; speedup vs baseline: 1.1951x; 1.1951x over previous
//
#include <hip/hip_runtime.h>

// x: (B, 65, 12) f32, only [:,0,:12] used. Row stride = 780 floats = 3120 B (16B-aligned).
// MLP: h=relu(q@W1+b1) [12->16]; blk=relu(h@W2+b2) [16->8];
// out = blk@(Ws@Wo) + (bs@Wo+bo) [8->3]  (Ws/Wo fold: no nonlinearity between them)
// d_out layout: out[B*3] then force_prev[B*3] = x[:,0,6:9]
//
// v3: round-1 structure (regular cached loads/stores — NT regressed 16.4->18.4,
// it defeats L2 write-combining of the 12B scalar stores). Keep only the
// load-before-staging reorder so row-fetch latency overlaps LDS setup.

__global__ __launch_bounds__(256) void mlp_fused(
    const float* __restrict__ x,
    const float* __restrict__ W1, const float* __restrict__ b1,
    const float* __restrict__ W2, const float* __restrict__ b2,
    const float* __restrict__ Ws, const float* __restrict__ bs,
    const float* __restrict__ Wo, const float* __restrict__ bo,
    float* __restrict__ out, int B)
{
    __shared__ float s[372];
    float* sW1 = s;          // 192 = 12*16
    float* sb1 = s + 192;    // 16
    float* sW2 = s + 208;    // 128 = 16*8
    float* sb2 = s + 336;    // 8
    float* sWc = s + 344;    // 24 = 8*3 folded Ws@Wo
    float* sbc = s + 368;    // 3  folded bs@Wo + bo

    const int t = threadIdx.x;
    const int idx = blockIdx.x * blockDim.x + t;

    // ---- issue the scattered row loads FIRST (latency overlaps staging) ----
    const float* row = x + (size_t)idx * 780;
    float4 v0, v1, v2;
    if (idx < B) {
        v0 = *reinterpret_cast<const float4*>(row);
        v1 = *reinterpret_cast<const float4*>(row + 4);
        v2 = *reinterpret_cast<const float4*>(row + 8);
    }

    // ---- stage weights (uniform, tiny) ----
    if (t < 192) sW1[t] = W1[t];
    if (t < 16)  sb1[t] = b1[t];
    if (t < 128) sW2[t] = W2[t];
    if (t < 8)   sb2[t] = b2[t];
    if (t < 24) {                      // Wc[k][j] = sum_m Ws[k,m]*Wo[m,j]
        int k = t / 3, j = t % 3;
        float acc = 0.f;
        #pragma unroll
        for (int m = 0; m < 16; ++m) acc = fmaf(Ws[k*16 + m], Wo[m*3 + j], acc);
        sWc[t] = acc;
    }
    if (t >= 24 && t < 27) {           // bc[j] = sum_m bs[m]*Wo[m,j] + bo[j]
        int j = t - 24;
        float acc = bo[j];
        #pragma unroll
        for (int m = 0; m < 16; ++m) acc = fmaf(bs[m], Wo[m*3 + j], acc);
        sbc[j] = acc;
    }
    __syncthreads();

    if (idx >= B) return;

    const float q[12] = {v0.x, v0.y, v0.z, v0.w,
                         v1.x, v1.y, v1.z, v1.w,
                         v2.x, v2.y, v2.z, v2.w};

    float h[16];
    #pragma unroll
    for (int j = 0; j < 16; ++j) {
        float acc = sb1[j];
        #pragma unroll
        for (int k = 0; k < 12; ++k) acc = fmaf(q[k], sW1[k*16 + j], acc);
        h[j] = fmaxf(acc, 0.f);
    }

    float blk[8];
    #pragma unroll
    for (int j = 0; j < 8; ++j) {
        float acc = sb2[j];
        #pragma unroll
        for (int k = 0; k < 16; ++k) acc = fmaf(h[k], sW2[k*8 + j], acc);
        blk[j] = fmaxf(acc, 0.f);
    }

    float o[3];
    #pragma unroll
    for (int j = 0; j < 3; ++j) {
        float acc = sbc[j];
        #pragma unroll
        for (int k = 0; k < 8; ++k) acc = fmaf(blk[k], sWc[k*3 + j], acc);
        o[j] = acc;
    }

    float* po = out + (size_t)idx * 3;
    po[0] = o[0]; po[1] = o[1]; po[2] = o[2];

    float* pf = out + (size_t)B * 3 + (size_t)idx * 3;
    pf[0] = q[6]; pf[1] = q[7]; pf[2] = q[8];
}

extern "C" void kernel_launch(void* const* d_in, const int* in_sizes, int n_in,
                              void* d_out, int out_size, void* d_ws, size_t ws_size,
                              hipStream_t stream) {
    const float* x  = (const float*)d_in[0];
    const float* W1 = (const float*)d_in[1];
    const float* b1 = (const float*)d_in[2];
    const float* W2 = (const float*)d_in[3];
    const float* b2 = (const float*)d_in[4];
    const float* Ws = (const float*)d_in[5];
    const float* bs = (const float*)d_in[6];
    const float* Wo = (const float*)d_in[7];
    const float* bo = (const float*)d_in[8];
    float* out = (float*)d_out;

    const int B = in_sizes[0] / (65 * 12);   // 262144
    const int blocks = (B + 255) / 256;      // 1024

    mlp_fused<<<blocks, 256, 0, stream>>>(x, W1, b1, W2, b2, Ws, bs, Wo, bo, out, B);
}